// Round 6
// baseline (919.576 us; speedup 1.0000x reference)
//
#include <hip/hip_runtime.h>
#include <math.h>

// AutoCorrelation (Autoformer) on MI355X.
// B*H=256, L=2048, E=64, fp32. FFT-based: per (b,h,e) series:
//   corr = IFFT( FFT(Q) * conj(FFT(K)) ), top-15 lags, softmax, 15-tap circular
//   gather of V. Q,K packed as one complex FFT (z = Q + iK).
// Pipeline R6: ktrans_qk -> ZT[bh][e][l](ws) ; kfft -> (w,d) ;
//   ktrans_v V->VT (ws, aliases dead ZT) ; kgather_bh VT->out (fused gather +
//   output transpose, per-bh XCD grouping).
//
// R6 changes (R5 post-mortem):
//  - kfft topk: value-only shfl max-reduce + __ballot owner lookup (was
//    (val,idx) pair reduce): ~45 ops/round vs ~80, biggest VALU block cut.
//  - kgather_bh: fused gather + transpose-out. Reads VT rows coalesced from
//    L2 (same-bh blocks pinned to one XCD via blockIdx remap, slice=512KB),
//    LDS 64x64 tile, coalesced float4 out writes. Kills OT round-trip
//    (268MB) + ktrans_o launch. VT moved to ws (d_out is live output now).

#define LEN   2048
#define BH    256
#define NE    64
#define NSER  (BH * NE)   // 16384
#define TOPK  15
#define NINF  (-INFINITY)

__device__ __forceinline__ int PC(int c) { return c + (c >> 4); }  // complex-unit pad

// twiddle W_2048^idx = (cos, sin) of -2*pi*idx/2048, idx in [0, 2048)
__device__ __forceinline__ void sincos_tw(int idx, float& c, float& s) {
#if __has_builtin(__builtin_amdgcn_sinf) && __has_builtin(__builtin_amdgcn_cosf)
  float rev = (float)idx * (-1.0f / 2048.0f);   // revolutions, in (-1, 0]
  s = __builtin_amdgcn_sinf(rev);
  c = __builtin_amdgcn_cosf(rev);
#else
  float ang = (float)idx * (-6.283185307179586f / 2048.0f);
  __sincosf(ang, &s, &c);
#endif
}

template <bool INV>
__device__ __forceinline__ void dft8(float* xr, float* xi) {
  const float sg = INV ? -1.f : 1.f;
  const float c = 0.70710678118654752440f;
  float s0r = xr[0] + xr[4], s0i = xi[0] + xi[4];
  float s1r = xr[0] - xr[4], s1i = xi[0] - xi[4];
  float s2r = xr[2] + xr[6], s2i = xi[2] + xi[6];
  float s3r = xr[2] - xr[6], s3i = xi[2] - xi[6];
  float E0r = s0r + s2r, E0i = s0i + s2i;
  float E2r = s0r - s2r, E2i = s0i - s2i;
  float E1r = s1r + sg * s3i, E1i = s1i - sg * s3r;
  float E3r = s1r - sg * s3i, E3i = s1i + sg * s3r;
  float u0r = xr[1] + xr[5], u0i = xi[1] + xi[5];
  float u1r = xr[1] - xr[5], u1i = xi[1] - xi[5];
  float u2r = xr[3] + xr[7], u2i = xi[3] + xi[7];
  float u3r = xr[3] - xr[7], u3i = xi[3] - xi[7];
  float O0r = u0r + u2r, O0i = u0i + u2i;
  float O2r = u0r - u2r, O2i = u0i - u2i;
  float O1r = u1r + sg * u3i, O1i = u1i - sg * u3r;
  float O3r = u1r - sg * u3i, O3i = u1i + sg * u3r;
  float G0r = O0r, G0i = O0i;
  float G1r = O1r * c + O1i * (sg * c), G1i = O1i * c - O1r * (sg * c);
  float G2r = sg * O2i, G2i = -sg * O2r;
  float G3r = -O3r * c + O3i * (sg * c), G3i = -O3i * c - O3r * (sg * c);
  xr[0] = E0r + G0r; xi[0] = E0i + G0i;
  xr[1] = E1r + G1r; xi[1] = E1i + G1i;
  xr[2] = E2r + G2r; xi[2] = E2i + G2i;
  xr[3] = E3r + G3r; xi[3] = E3i + G3i;
  xr[4] = E0r - G0r; xi[4] = E0i - G0i;
  xr[5] = E1r - G1r; xi[5] = E1i - G1i;
  xr[6] = E2r - G2r; xi[6] = E2i - G2i;
  xr[7] = E3r - G3r; xi[7] = E3i - G3i;
}

template <bool INV>
__device__ __forceinline__ void dft4(float* xr, float* xi) {
  const float sg = INV ? -1.f : 1.f;
  float s0r = xr[0] + xr[2], s0i = xi[0] + xi[2];
  float s1r = xr[0] - xr[2], s1i = xi[0] - xi[2];
  float s2r = xr[1] + xr[3], s2i = xi[1] + xi[3];
  float s3r = xr[1] - xr[3], s3i = xi[1] - xi[3];
  xr[0] = s0r + s2r;        xi[0] = s0i + s2i;
  xr[1] = s1r + sg * s3i;   xi[1] = s1i - sg * s3r;
  xr[2] = s0r - s2r;        xi[2] = s0i - s2i;
  xr[3] = s1r - sg * s3i;   xi[3] = s1i + sg * s3r;
}

// In-place Stockham radix-8 stage on interleaved complex LDS buffer.
// Twiddles: one sincos for W^(s*p), then complex recurrence for powers.
template <bool INV>
__device__ __forceinline__ void stage8_ip(float2* CB, int s, int sLog, int t) {
  float ar[8], ai[8];
#pragma unroll
  for (int r = 0; r < 8; ++r) {
    float2 v = CB[PC(t + 256 * r)];
    ar[r] = v.x; ai[r] = v.y;
  }
  __syncthreads();
  dft8<INV>(ar, ai);
  int q = t & (s - 1), p = t >> sLog;
  int ob = q + 8 * s * p;
  float c1, s1; sincos_tw(s * p, c1, s1);
  if (INV) s1 = -s1;
  CB[PC(ob)] = make_float2(ar[0], ai[0]);
  float wc = c1, wsn = s1;
#pragma unroll
  for (int j = 1; j < 8; ++j) {
    float zr = ar[j] * wc - ai[j] * wsn;
    float zi = ar[j] * wsn + ai[j] * wc;
    CB[PC(ob + s * j)] = make_float2(zr, zi);
    if (j < 7) {
      float nc = wc * c1 - wsn * s1;
      wsn = wc * s1 + wsn * c1;
      wc = nc;
    }
  }
  __syncthreads();
}

// ---------------- transpose kernels (64x64 LDS tiles, float4 global) --------

__global__ __launch_bounds__(256) void ktrans_qk(const float* __restrict__ Q,
                                                 const float* __restrict__ K,
                                                 float2* __restrict__ ZT) {
  int bh = blockIdx.x >> 5, l0 = (blockIdx.x & 31) * 64;
  __shared__ float sq[64][65], sk[64][65];
  int t = threadIdx.x;
  const float4* Qb = (const float4*)(Q + ((size_t)bh * LEN + l0) * NE);
  const float4* Kb = (const float4*)(K + ((size_t)bh * LEN + l0) * NE);
  int x = t & 15, c4 = x * 4;
#pragma unroll
  for (int it = 0; it < 4; ++it) {
    int row = (t >> 4) + it * 16;
    float4 q4 = Qb[row * 16 + x];
    float4 k4 = Kb[row * 16 + x];
    sq[row][c4 + 0] = q4.x; sq[row][c4 + 1] = q4.y;
    sq[row][c4 + 2] = q4.z; sq[row][c4 + 3] = q4.w;
    sk[row][c4 + 0] = k4.x; sk[row][c4 + 1] = k4.y;
    sk[row][c4 + 2] = k4.z; sk[row][c4 + 3] = k4.w;
  }
  __syncthreads();
  float2* Zb = ZT + (size_t)bh * NE * LEN + l0;
  int l2 = (t & 31) * 2;
#pragma unroll
  for (int it = 0; it < 8; ++it) {
    int e = (t >> 5) + it * 8;
    float4 o;
    o.x = sq[l2][e];     o.y = sk[l2][e];
    o.z = sq[l2 + 1][e]; o.w = sk[l2 + 1][e];
    *(float4*)&Zb[(size_t)e * LEN + l2] = o;
  }
}

__global__ __launch_bounds__(256) void ktrans_v(const float* __restrict__ src,
                                                float* __restrict__ dst) {
  int bh = blockIdx.x >> 5, l0 = (blockIdx.x & 31) * 64;
  __shared__ float sT[64][65];
  int t = threadIdx.x;
  const float4* Sb = (const float4*)(src + ((size_t)bh * LEN + l0) * NE);
  int x = t & 15, c4 = x * 4;
#pragma unroll
  for (int it = 0; it < 4; ++it) {
    int row = (t >> 4) + it * 16;
    float4 v4 = Sb[row * 16 + x];
    sT[row][c4 + 0] = v4.x; sT[row][c4 + 1] = v4.y;
    sT[row][c4 + 2] = v4.z; sT[row][c4 + 3] = v4.w;
  }
  __syncthreads();
  float* Db = dst + (size_t)bh * NE * LEN + l0;
  int l4 = x * 4;
#pragma unroll
  for (int it = 0; it < 4; ++it) {
    int e = (t >> 4) + it * 16;
    float4 o;
    o.x = sT[l4 + 0][e]; o.y = sT[l4 + 1][e];
    o.z = sT[l4 + 2][e]; o.w = sT[l4 + 3][e];
    *(float4*)&Db[(size_t)e * LEN + l4] = o;
  }
}

// ---------------- FFT + corr + topk + softmax ----------------

__global__ __launch_bounds__(256) void kfft(const float2* __restrict__ ZT,
                                            float* __restrict__ Wt,
                                            int* __restrict__ Dl) {
  __shared__ float2 CB[2176];            // 2048 complex + pad (17.4 KB)
  __shared__ float mv[64]; __shared__ int mi[64];
  const int t = threadIdx.x;
  const int wv = t >> 6, ln = t & 63;
  const float2* z = ZT + (size_t)blockIdx.x * LEN;

  // ---- forward stage 1 (s=1): global -> LDS scatter ----
  {
    float ar[8], ai[8];
#pragma unroll
    for (int r = 0; r < 8; ++r) {
      float2 v = z[t + 256 * r];
      ar[r] = v.x; ai[r] = v.y;
    }
    dft8<false>(ar, ai);
    float c1, s1; sincos_tw(t, c1, s1);
    CB[PC(8 * t)] = make_float2(ar[0], ai[0]);
    float wc = c1, wsn = s1;
#pragma unroll
    for (int j = 1; j < 8; ++j) {
      float zr = ar[j] * wc - ai[j] * wsn;
      float zi = ar[j] * wsn + ai[j] * wc;
      CB[PC(8 * t + j)] = make_float2(zr, zi);
      if (j < 7) {
        float nc = wc * c1 - wsn * s1;
        wsn = wc * s1 + wsn * c1;
        wc = nc;
      }
    }
  }
  __syncthreads();
  stage8_ip<false>(CB, 8, 3, t);
  stage8_ip<false>(CB, 64, 6, t);
  // ---- forward radix-4 (s=512, no twiddle): thread-private slots ----
#pragma unroll
  for (int h = 0; h < 2; ++h) {
    int u = t + 256 * h;
    float xr[4], xi[4];
#pragma unroll
    for (int r = 0; r < 4; ++r) {
      float2 v = CB[PC(u + 512 * r)];
      xr[r] = v.x; xi[r] = v.y;
    }
    dft4<false>(xr, xi);
#pragma unroll
    for (int j = 0; j < 4; ++j) CB[PC(u + 512 * j)] = make_float2(xr[j], xi[j]);
  }
  __syncthreads();

  // ---- spectrum: C = X*conj(Y), pair-based (f in [0,1024), m = 2048-f) ----
  {
    float2 zf[4], zm[4];
#pragma unroll
    for (int r = 0; r < 4; ++r) {
      int f = t + 256 * r;
      int m = (LEN - f) & (LEN - 1);
      zf[r] = CB[PC(f)]; zm[r] = CB[PC(m)];
    }
    float2 e1 = make_float2(0.f, 0.f);
    if (t == 0) e1 = CB[PC(1024)];
    __syncthreads();
#pragma unroll
    for (int r = 0; r < 4; ++r) {
      int f = t + 256 * r;
      int m = (LEN - f) & (LEN - 1);
      float Xr = 0.5f * (zf[r].x + zm[r].x), Xi = 0.5f * (zf[r].y - zm[r].y);
      float Yr = 0.5f * (zf[r].y + zm[r].y), Yi = -0.5f * (zf[r].x - zm[r].x);
      CB[PC(f)] = make_float2(Xr * Yr + Xi * Yi, Xi * Yr - Xr * Yi);
      float Xr2 = 0.5f * (zm[r].x + zf[r].x), Xi2 = 0.5f * (zm[r].y - zf[r].y);
      float Yr2 = 0.5f * (zf[r].y + zm[r].y), Yi2 = -0.5f * (zm[r].x - zf[r].x);
      CB[PC(m)] = make_float2(Xr2 * Yr2 + Xi2 * Yi2, Xi2 * Yr2 - Xr2 * Yi2);
    }
    if (t == 0) CB[PC(1024)] = make_float2(e1.x * e1.y, 0.f);
  }
  __syncthreads();

  // ---- inverse FFT: 3 in-place radix-8 stages + final radix-4 into regs ----
  stage8_ip<true>(CB, 1, 0, t);
  stage8_ip<true>(CB, 8, 3, t);
  stage8_ip<true>(CB, 64, 6, t);
  float rv[8]; int ri[8];
#pragma unroll
  for (int h = 0; h < 2; ++h) {
    int u = t + 256 * h;
    float xr[4], xi[4];
#pragma unroll
    for (int r = 0; r < 4; ++r) {
      float2 v = CB[PC(u + 512 * r)];
      xr[r] = v.x; xi[r] = v.y;
    }
    dft4<true>(xr, xi);
#pragma unroll
    for (int j = 0; j < 4; ++j) {
      rv[h * 4 + j] = xr[j];          // corr * 2048
      ri[h * 4 + j] = u + 512 * j;    // lag index
    }
  }

  // ---- per-lane Batcher sort-8 (desc by value) ----
#define CE(i, j) { bool sw = rv[i] < rv[j];                                   \
    float tv = sw ? rv[j] : rv[i]; rv[j] = sw ? rv[i] : rv[j]; rv[i] = tv;    \
    int tx = sw ? ri[j] : ri[i];  ri[j] = sw ? ri[i] : ri[j];  ri[i] = tx; }
  CE(0,1) CE(2,3) CE(4,5) CE(6,7)
  CE(0,2) CE(1,3) CE(4,6) CE(5,7)
  CE(1,2) CE(5,6)
  CE(0,4) CE(1,5) CE(2,6) CE(3,7)
  CE(2,4) CE(3,5)
  CE(1,2) CE(3,4) CE(5,6)
#undef CE

  // ---- per-wave top-15: value-only max reduce + ballot owner ----
  for (int it = 0; it < TOPK; ++it) {
    float bv = rv[0];
#pragma unroll
    for (int off = 32; off >= 1; off >>= 1)
      bv = fmaxf(bv, __shfl_xor(bv, off));
    unsigned long long m = __ballot(rv[0] == bv);
    int winlane = __ffsll(m) - 1;
    int widx = __shfl(ri[0], winlane);
    if (ln == 0) { mv[wv * 16 + it] = bv; mi[wv * 16 + it] = widx; }
    if (ln == winlane) {  // pop my head
#pragma unroll
      for (int k = 0; k < 7; ++k) { rv[k] = rv[k + 1]; ri[k] = ri[k + 1]; }
      rv[7] = NINF;
    }
  }
  __syncthreads();

  // ---- single-wave merge of 4x15 + softmax, value-only ----
  if (wv == 0) {
    float v = ((ln & 15) < TOPK) ? mv[ln] : NINF;
    int ix = ((ln & 15) < TOPK) ? mi[ln] : 0;
    float myv = NINF; int myi = 0;
    for (int it = 0; it < TOPK; ++it) {
      float bv = v;
#pragma unroll
      for (int off = 32; off >= 1; off >>= 1)
        bv = fmaxf(bv, __shfl_xor(bv, off));
      unsigned long long m = __ballot(v == bv);
      int winlane = __ffsll(m) - 1;
      int widx = __shfl(ix, winlane);
      if (ln == it) { myv = bv; myi = widx; }
      if (ln == winlane) v = NINF;
    }
    const float scl = 1.0f / 2048.0f;
    float vmax = __shfl(myv, 0);  // first selected == max
    float e = (ln < TOPK) ? expf((myv - vmax) * scl) : 0.f;
    float ssum = e;
#pragma unroll
    for (int off = 1; off < 16; off <<= 1) ssum += __shfl_xor(ssum, off);
    if (ln < TOPK) {
      Wt[(size_t)blockIdx.x * 16 + ln] = e / ssum;
      Dl[(size_t)blockIdx.x * 16 + ln] = myi;
    }
  }
}

// ------- fused gather + output transpose, block per (bh, l-chunk of 256) ----
// blockIdx remap: d%8 = XCD; XCD x serves bh in [x*32,(x+1)*32) so each bh's
// 512KB VT slice stays resident in ONE XCD's L2 across its 8 l-chunk blocks.

__global__ __launch_bounds__(256) void kgather_bh(const float* __restrict__ VT,
                                                  const float* __restrict__ Wt,
                                                  const int* __restrict__ Dl,
                                                  float* __restrict__ out) {
  int d = blockIdx.x;
  int x = d & 7, k = d >> 3;          // x = xcd slot, k in [0,256)
  int bh = x * 32 + (k >> 3);
  int ls = k & 7;                     // l-chunk of 256
  const int t = threadIdx.x;
  const int wv = t >> 6, ln = t & 63;

  __shared__ float lw[64][16];
  __shared__ int   ldl[64][16];
  __shared__ float tile[64][65];

  const float* Wb = Wt + (size_t)bh * NE * 16;
  const int*   Db = Dl + (size_t)bh * NE * 16;
#pragma unroll
  for (int i = 0; i < 4; ++i) {
    int idx = t + i * 256;
    lw[idx >> 4][idx & 15] = Wb[idx];
    ldl[idx >> 4][idx & 15] = Db[idx];
  }
  __syncthreads();

  const float* Vbh = VT + (size_t)bh * NE * LEN;
  for (int lt = 0; lt < 4; ++lt) {
    int l0 = ls * 256 + lt * 64;
    for (int ei = 0; ei < 16; ++ei) {
      int e = ei * 4 + wv;
      const float* vrow = Vbh + (size_t)e * LEN;
      float acc = 0.f;
#pragma unroll
      for (int i = 0; i < TOPK; ++i) {
        int dd = ldl[e][i];
        float ww = lw[e][i];
        acc += ww * vrow[(l0 + ln + dd) & (LEN - 1)];
      }
      tile[ln][e] = acc;
    }
    __syncthreads();
    // write 64x64 tile, coalesced: thread t -> row t>>2, 16 cols at (t&3)*16
    int r = t >> 2, c0 = (t & 3) * 16;
    float* orow = out + ((size_t)bh * LEN + l0 + r) * NE + c0;
#pragma unroll
    for (int j = 0; j < 4; ++j) {
      float4 o = make_float4(tile[r][c0 + 4 * j + 0], tile[r][c0 + 4 * j + 1],
                             tile[r][c0 + 4 * j + 2], tile[r][c0 + 4 * j + 3]);
      ((float4*)orow)[j] = o;
    }
    __syncthreads();
  }
}

extern "C" void kernel_launch(void* const* d_in, const int* in_sizes, int n_in,
                              void* d_out, int out_size, void* d_ws, size_t ws_size,
                              hipStream_t stream) {
  const float* Q = (const float*)d_in[0];
  const float* K = (const float*)d_in[1];
  const float* V = (const float*)d_in[2];
  float* out = (float*)d_out;
  char* ws = (char*)d_ws;

  const size_t ZT_BYTES = (size_t)NSER * LEN * sizeof(float2);  // 256 MiB
  float2* ZT = (float2*)ws;
  float* Wt = (float*)(ws + ZT_BYTES);
  int* Dl = (int*)(ws + ZT_BYTES + (size_t)NSER * 16 * sizeof(float));
  float* VT = (float*)ws;   // aliases ZT (dead after kfft); d_out stays output

  ktrans_qk<<<BH * 32, 256, 0, stream>>>(Q, K, ZT);
  kfft<<<NSER, 256, 0, stream>>>(ZT, Wt, Dl);
  ktrans_v<<<BH * 32, 256, 0, stream>>>(V, VT);
  kgather_bh<<<BH * 8, 256, 0, stream>>>(VT, Wt, Dl, out);
}